// Round 1
// baseline (1878.995 us; speedup 1.0000x reference)
//
#include <hip/hip_runtime.h>

#define B_ 4
#define S_ 2048
#define D_ 1024
#define H_ 16
#define E_ 64
#define M_ (B_*S_)   // 8192
#define LP 68        // LDS pitch in floats: 68*4B = 272B = 17*16B (keeps b128 16B-aligned, breaks pow2 bank stride)

__device__ __forceinline__ void fma44(float acc[4][4], float4 a, float4 b) {
    const float av[4] = {a.x, a.y, a.z, a.w};
    const float bv[4] = {b.x, b.y, b.z, b.w};
    #pragma unroll
    for (int i = 0; i < 4; ++i)
        #pragma unroll
        for (int j = 0; j < 4; ++j)
            acc[i][j] += av[i] * bv[j];
}

// ---------------- QKV projection ----------------
// out[w][b,h,s,e] = sum_d x[b,s,d] * W[w][h,d,e]
// grid: (M_/64, 3*H_), block 256. 64x64 tile, BK=16, 4x4 per thread.
__global__ __launch_bounds__(256) void qkv_proj(
    const float* __restrict__ x,
    const float* __restrict__ Wq,
    const float* __restrict__ Wk,
    const float* __restrict__ Wv,
    float* __restrict__ qo,
    float* __restrict__ ko,
    float* __restrict__ vo)
{
    const int m0 = blockIdx.x * 64;
    const int wh = blockIdx.y;     // 0..47
    const int w  = wh >> 4;        // 0:q 1:k 2:v
    const int h  = wh & 15;
    const float* W = (w == 0 ? Wq : (w == 1 ? Wk : Wv)) + (size_t)h * D_ * E_;
    float* out = (w == 0 ? qo : (w == 1 ? ko : vo));

    __shared__ float As[16 * LP];  // As[k][m] (transposed x tile)
    __shared__ float Bs[16 * LP];  // Bs[k][e] (natural W tile)

    const int t  = threadIdx.x;
    const int tx = t & 15;
    const int ty = t >> 4;
    const int arow = t >> 2, aq = t & 3;   // x-tile loader: 64 rows x 4 quads
    const int brow = t >> 4, bc = t & 15;  // W-tile loader: 16 rows x 16 quads

    float acc[4][4] = {};

    for (int k0 = 0; k0 < D_; k0 += 16) {
        __syncthreads();
        {
            float4 g = *(const float4*)(x + (size_t)(m0 + arow) * D_ + k0 + aq * 4);
            As[(aq * 4 + 0) * LP + arow] = g.x;
            As[(aq * 4 + 1) * LP + arow] = g.y;
            As[(aq * 4 + 2) * LP + arow] = g.z;
            As[(aq * 4 + 3) * LP + arow] = g.w;
            float4 gw = *(const float4*)(W + (size_t)(k0 + brow) * E_ + bc * 4);
            *(float4*)(&Bs[brow * LP + bc * 4]) = gw;
        }
        __syncthreads();
        #pragma unroll
        for (int kk = 0; kk < 16; ++kk) {
            float4 a = *(const float4*)(&As[kk * LP + ty * 4]);
            float4 b = *(const float4*)(&Bs[kk * LP + tx * 4]);
            fma44(acc, a, b);
        }
    }

    #pragma unroll
    for (int i = 0; i < 4; ++i) {
        int row = m0 + ty * 4 + i;
        int b = row >> 11;          // / S_
        int s = row & (S_ - 1);
        float4 r = make_float4(acc[i][0], acc[i][1], acc[i][2], acc[i][3]);
        *(float4*)(out + ((size_t)(b * H_ + h) * S_ + s) * E_ + tx * 4) = r;
    }
}

// ---------------- Flash attention (causal) ----------------
// grid: (S_/64, B_*H_), block 256. 64 q-rows per block, 64-col kv tiles, j<=qt.
__global__ __launch_bounds__(256) void flash_attn(
    const float* __restrict__ qi,
    const float* __restrict__ ki,
    const float* __restrict__ vi,
    float* __restrict__ ao)   // [B,S,D] concat-head layout
{
    const int qt = blockIdx.x;     // 0..31
    const int bh = blockIdx.y;     // 0..63
    const int b  = bh >> 4;
    const int h  = bh & 15;

    const float* qb = qi + (size_t)bh * S_ * E_;
    const float* kb = ki + (size_t)bh * S_ * E_;
    const float* vb = vi + (size_t)bh * S_ * E_;

    __shared__ float Qs[64 * LP];  // Qs[e][i]
    __shared__ float Ks[64 * LP];  // Ks[e][j]
    __shared__ float Vs[64 * LP];  // Vs[j][e]
    __shared__ float Ps[64 * LP];  // Ps[j][i]

    const int t  = threadIdx.x;
    const int tx = t & 15;
    const int ty = t >> 4;
    const float NEG_INF = -__builtin_inff();

    // load Q tile transposed
    #pragma unroll
    for (int it = 0; it < 4; ++it) {
        int idx = it * 256 + t;
        int row = idx >> 4, qd = idx & 15;
        float4 g = *(const float4*)(qb + (size_t)(qt * 64 + row) * E_ + qd * 4);
        Qs[(qd * 4 + 0) * LP + row] = g.x;
        Qs[(qd * 4 + 1) * LP + row] = g.y;
        Qs[(qd * 4 + 2) * LP + row] = g.z;
        Qs[(qd * 4 + 3) * LP + row] = g.w;
    }

    float o[4][4] = {};
    float mrun[4], lrun[4];
    #pragma unroll
    for (int i = 0; i < 4; ++i) { mrun[i] = NEG_INF; lrun[i] = 0.f; }

    for (int jt = 0; jt <= qt; ++jt) {
        __syncthreads();
        // stage K (transposed) and V (natural)
        #pragma unroll
        for (int it = 0; it < 4; ++it) {
            int idx = it * 256 + t;
            int row = idx >> 4, qd = idx & 15;
            float4 g = *(const float4*)(kb + (size_t)(jt * 64 + row) * E_ + qd * 4);
            Ks[(qd * 4 + 0) * LP + row] = g.x;
            Ks[(qd * 4 + 1) * LP + row] = g.y;
            Ks[(qd * 4 + 2) * LP + row] = g.z;
            Ks[(qd * 4 + 3) * LP + row] = g.w;
            float4 gv = *(const float4*)(vb + (size_t)(jt * 64 + row) * E_ + qd * 4);
            *(float4*)(&Vs[row * LP + qd * 4]) = gv;
        }
        __syncthreads();

        // S = Q K^T  (rows ty*4.., cols tx*4..)
        float sc[4][4] = {};
        #pragma unroll 8
        for (int e = 0; e < 64; ++e) {
            float4 a = *(const float4*)(&Qs[e * LP + ty * 4]);
            float4 k4 = *(const float4*)(&Ks[e * LP + tx * 4]);
            fma44(sc, a, k4);
        }

        // scale + causal mask (only diagonal tile needs masking)
        #pragma unroll
        for (int i = 0; i < 4; ++i)
            #pragma unroll
            for (int j = 0; j < 4; ++j) {
                sc[i][j] *= 0.125f;  // E^-0.5
                if (jt == qt && (tx * 4 + j) > (ty * 4 + i)) sc[i][j] = NEG_INF;
            }

        // online softmax per row (rows replicated across the 16 tx lanes)
        #pragma unroll
        for (int i = 0; i < 4; ++i) {
            float mx = fmaxf(fmaxf(sc[i][0], sc[i][1]), fmaxf(sc[i][2], sc[i][3]));
            #pragma unroll
            for (int off = 1; off < 16; off <<= 1) mx = fmaxf(mx, __shfl_xor(mx, off));
            float mnew  = fmaxf(mrun[i], mx);
            float alpha = __expf(mrun[i] - mnew);
            float rs = 0.f;
            #pragma unroll
            for (int j = 0; j < 4; ++j) { sc[i][j] = __expf(sc[i][j] - mnew); rs += sc[i][j]; }
            #pragma unroll
            for (int off = 1; off < 16; off <<= 1) rs += __shfl_xor(rs, off);
            lrun[i] = lrun[i] * alpha + rs;
            mrun[i] = mnew;
            #pragma unroll
            for (int j = 0; j < 4; ++j) o[i][j] *= alpha;
        }

        // store P transposed: Ps[j][i] (float4 along i)
        #pragma unroll
        for (int j = 0; j < 4; ++j) {
            float4 pv = make_float4(sc[0][j], sc[1][j], sc[2][j], sc[3][j]);
            *(float4*)(&Ps[(tx * 4 + j) * LP + ty * 4]) = pv;
        }
        __syncthreads();

        // O += P V  (rows ty*4.., e-cols tx*4..)
        #pragma unroll 8
        for (int jd = 0; jd < 64; ++jd) {
            float4 p4 = *(const float4*)(&Ps[jd * LP + ty * 4]);
            float4 v4 = *(const float4*)(&Vs[jd * LP + tx * 4]);
            fma44(o, p4, v4);
        }
    }

    // epilogue: normalize and write concat-head layout
    #pragma unroll
    for (int i = 0; i < 4; ++i) {
        float inv = 1.0f / lrun[i];
        float4 r = make_float4(o[i][0]*inv, o[i][1]*inv, o[i][2]*inv, o[i][3]*inv);
        int srow = qt * 64 + ty * 4 + i;
        *(float4*)(ao + (size_t)(b * S_ + srow) * D_ + h * E_ + tx * 4) = r;
    }
}

// ---------------- Output projection ----------------
// out[m][n] = sum_k a[m][k] * Wp[n][k] + bp[n]
// grid: (M_/64, D_/64), block 256.
__global__ __launch_bounds__(256) void out_proj(
    const float* __restrict__ a,
    const float* __restrict__ Wp,
    const float* __restrict__ bp,
    float* __restrict__ out)
{
    const int m0 = blockIdx.x * 64;
    const int n0 = blockIdx.y * 64;

    __shared__ float As[16 * LP];  // As[k][m]
    __shared__ float Bs[16 * LP];  // Bs[k][n] = Wp[n][k]

    const int t  = threadIdx.x;
    const int tx = t & 15;
    const int ty = t >> 4;
    const int arow = t >> 2, aq = t & 3;

    float acc[4][4] = {};

    for (int k0 = 0; k0 < D_; k0 += 16) {
        __syncthreads();
        {
            float4 g = *(const float4*)(a + (size_t)(m0 + arow) * D_ + k0 + aq * 4);
            As[(aq * 4 + 0) * LP + arow] = g.x;
            As[(aq * 4 + 1) * LP + arow] = g.y;
            As[(aq * 4 + 2) * LP + arow] = g.z;
            As[(aq * 4 + 3) * LP + arow] = g.w;
            float4 gw = *(const float4*)(Wp + (size_t)(n0 + arow) * D_ + k0 + aq * 4);
            Bs[(aq * 4 + 0) * LP + arow] = gw.x;
            Bs[(aq * 4 + 1) * LP + arow] = gw.y;
            Bs[(aq * 4 + 2) * LP + arow] = gw.z;
            Bs[(aq * 4 + 3) * LP + arow] = gw.w;
        }
        __syncthreads();
        #pragma unroll
        for (int kk = 0; kk < 16; ++kk) {
            float4 av = *(const float4*)(&As[kk * LP + ty * 4]);
            float4 bv = *(const float4*)(&Bs[kk * LP + tx * 4]);
            fma44(acc, av, bv);
        }
    }

    float4 bpv = *(const float4*)(bp + n0 + tx * 4);
    #pragma unroll
    for (int i = 0; i < 4; ++i) {
        int row = m0 + ty * 4 + i;
        float4 r = make_float4(acc[i][0] + bpv.x, acc[i][1] + bpv.y,
                               acc[i][2] + bpv.z, acc[i][3] + bpv.w);
        *(float4*)(out + (size_t)row * D_ + n0 + tx * 4) = r;
    }
}

extern "C" void kernel_launch(void* const* d_in, const int* in_sizes, int n_in,
                              void* d_out, int out_size, void* d_ws, size_t ws_size,
                              hipStream_t stream) {
    const float* x  = (const float*)d_in[0];
    const float* Wq = (const float*)d_in[1];
    const float* Wk = (const float*)d_in[2];
    const float* Wv = (const float*)d_in[3];
    const float* Wp = (const float*)d_in[4];
    const float* bp = (const float*)d_in[5];
    float* out = (float*)d_out;

    float* ws = (float*)d_ws;
    const size_t QSZ = (size_t)B_ * H_ * S_ * E_;   // 8388608 floats
    float* q    = ws;
    float* k    = ws + QSZ;
    float* v    = ws + 2 * QSZ;
    float* attn = ws + 3 * QSZ;                     // [B,S,D] concat

    qkv_proj <<<dim3(M_ / 64, 3 * H_), 256, 0, stream>>>(x, Wq, Wk, Wv, q, k, v);
    flash_attn<<<dim3(S_ / 64, B_ * H_), 256, 0, stream>>>(q, k, v, attn);
    out_proj <<<dim3(M_ / 64, D_ / 64), 256, 0, stream>>>(attn, Wp, bp, out);
}

// Round 2
// 343.201 us; speedup vs baseline: 5.4749x; 5.4749x over previous
//
#include <hip/hip_runtime.h>

#define B_ 4
#define S_ 2048
#define D_ 1024
#define H_ 16
#define E_ 64
#define M_ (B_*S_)   // 8192

typedef __attribute__((ext_vector_type(8))) short short8;   // 8 bf16 = 4 VGPRs (MFMA A/B frag)
typedef __attribute__((ext_vector_type(4))) float floatx4;  // MFMA C/D frag

// async global->LDS, 16B per lane; dest must be linear (wave base + lane*16)
#define GLD16(g, l) __builtin_amdgcn_global_load_lds( \
    (const __attribute__((address_space(1))) unsigned*)(g), \
    (__attribute__((address_space(3))) unsigned*)(l), 16, 0, 0)

__device__ __forceinline__ ushort f2b(float f) {   // fp32 -> bf16 RNE
    union { float f; unsigned u; } v; v.f = f;
    unsigned r = v.u + 0x7fffu + ((v.u >> 16) & 1u);
    return (ushort)(r >> 16);
}
__device__ __forceinline__ float fast_exp2(float x) {
#if __has_builtin(__builtin_amdgcn_exp2f)
    return __builtin_amdgcn_exp2f(x);
#else
    float r; asm("v_exp_f32 %0, %1" : "=v"(r) : "v"(x)); return r;
#endif
}

// ---------------- plain cast fp32 -> bf16 (vector8) ----------------
__global__ __launch_bounds__(256) void cast_bf16(const float* __restrict__ in,
                                                 ushort* __restrict__ out, int n8) {
    int i = blockIdx.x * 256 + threadIdx.x;
    int stride = gridDim.x * 256;
    for (; i < n8; i += stride) {
        float4 a = ((const float4*)in)[2 * i];
        float4 b = ((const float4*)in)[2 * i + 1];
        short8 o;
        o[0] = (short)f2b(a.x); o[1] = (short)f2b(a.y);
        o[2] = (short)f2b(a.z); o[3] = (short)f2b(a.w);
        o[4] = (short)f2b(b.x); o[5] = (short)f2b(b.y);
        o[6] = (short)f2b(b.z); o[7] = (short)f2b(b.w);
        ((short8*)out)[i] = o;
    }
}

// ---------------- W cast+transpose: [48][D][E] fp32 -> [48][E][D] bf16 ----------------
__global__ __launch_bounds__(256) void transpose_w(const float* __restrict__ Wq,
                                                   const float* __restrict__ Wk,
                                                   const float* __restrict__ Wv,
                                                   ushort* __restrict__ wt) {
    int g = blockIdx.y;                 // 0..47 (w*16+h)
    int d0 = blockIdx.x * 64;
    const float* W = (g < 16 ? Wq : (g < 32 ? Wk : Wv)) + (size_t)(g & 15) * (D_ * E_);
    __shared__ __align__(16) ushort T[64 * 80];   // T[e][d-col], pitch 80
    int t = threadIdx.x;
    #pragma unroll
    for (int it = 0; it < 4; ++it) {               // 64 d-rows x 16 float4 cols
        int i = it * 256 + t;
        int r = i >> 4, c = i & 15;
        float4 x = *(const float4*)(W + (size_t)(d0 + r) * E_ + c * 4);
        T[(c * 4 + 0) * 80 + r] = f2b(x.x);
        T[(c * 4 + 1) * 80 + r] = f2b(x.y);
        T[(c * 4 + 2) * 80 + r] = f2b(x.z);
        T[(c * 4 + 3) * 80 + r] = f2b(x.w);
    }
    __syncthreads();
    #pragma unroll
    for (int it = 0; it < 2; ++it) {               // 64 e-rows x 8 chunks of 8
        int i = it * 256 + t;
        int e = i >> 3, c = i & 7;
        short8 x = *(const short8*)&T[e * 80 + c * 8];
        *(short8*)&wt[((size_t)g * E_ + e) * D_ + d0 + c * 8] = x;
    }
}

// ---------------- V transpose: [bh][S][E] -> [bh][E][S] (bf16) ----------------
__global__ __launch_bounds__(256) void transpose_v(const ushort* __restrict__ v,
                                                   ushort* __restrict__ vt) {
    int s0 = blockIdx.x * 64;
    int bh = blockIdx.y;
    __shared__ __align__(16) ushort T[64 * 80];   // T[e][s-col]
    int t = threadIdx.x;
    #pragma unroll
    for (int it = 0; it < 2; ++it) {
        int i = it * 256 + t;
        int r = i >> 3, c = i & 7;                 // s-row r, e-chunk c
        short8 x = *(const short8*)&v[((size_t)bh * S_ + s0 + r) * E_ + c * 8];
        #pragma unroll
        for (int j = 0; j < 8; ++j) T[(c * 8 + j) * 80 + r] = (ushort)x[j];
    }
    __syncthreads();
    #pragma unroll
    for (int it = 0; it < 2; ++it) {
        int i = it * 256 + t;
        int e = i >> 3, c = i & 7;
        short8 x = *(const short8*)&T[e * 80 + c * 8];
        *(short8*)&vt[((size_t)bh * E_ + e) * S_ + s0 + c * 8] = x;
    }
}

// ---------------- QKV GEMM: [8192 x 1024] x [1024 x 64] per (w,h), bf16 MFMA ----------------
// tile 256x64, BK=32, 4 waves (64 rows each, full 64 cols), 16 mfma / wave / K-step.
// LDS chunk-XOR swizzle: row of 4 16B-chunks, c' = c ^ ((r>>1)&3) -> uniform banks on ds_read_b128.
__global__ __launch_bounds__(256) void gemm_qkv(const ushort* __restrict__ xb,
                                                const ushort* __restrict__ wt,
                                                ushort* __restrict__ qkv) {
    const int m0 = blockIdx.x * 256;
    const int wh = blockIdx.y;           // 0..47
    const ushort* Wg = wt + (size_t)wh * (E_ * D_);
    ushort* outw = qkv + (size_t)(wh >> 4) * ((size_t)B_ * H_ * S_ * E_);
    const int h = wh & 15;

    __shared__ __align__(16) ushort As[256 * 32];   // [256][32] swizzled
    __shared__ __align__(16) ushort Bs[64 * 32];    // [64][32]  swizzled

    const int t = threadIdx.x, l = t & 63, wid = t >> 6;
    floatx4 acc[4][4] = {};

    for (int k0 = 0; k0 < D_; k0 += 32) {
        __syncthreads();
        #pragma unroll
        for (int it = 0; it < 4; ++it) {            // A: 1024 chunks
            int i = it * 256 + t;
            int r = i >> 2, cs = i & 3;
            int c = cs ^ ((r >> 1) & 3);
            GLD16(xb + (size_t)(m0 + r) * D_ + k0 + c * 8, &As[i * 8]);
        }
        {                                            // B: 256 chunks
            int r = t >> 2, cs = t & 3;
            int c = cs ^ ((r >> 1) & 3);
            GLD16(Wg + (size_t)r * D_ + k0 + c * 8, &Bs[t * 8]);
        }
        __syncthreads();

        short8 af[4], bf[4];
        #pragma unroll
        for (int mf = 0; mf < 4; ++mf) {
            int row = wid * 64 + 16 * mf + (l & 15);
            int c = (l >> 4) ^ ((row >> 1) & 3);
            af[mf] = *(const short8*)&As[row * 32 + c * 8];
        }
        #pragma unroll
        for (int nf = 0; nf < 4; ++nf) {
            int row = 16 * nf + (l & 15);
            int c = (l >> 4) ^ ((row >> 1) & 3);
            bf[nf] = *(const short8*)&Bs[row * 32 + c * 8];
        }
        #pragma unroll
        for (int mf = 0; mf < 4; ++mf)
            #pragma unroll
            for (int nf = 0; nf < 4; ++nf)
                acc[mf][nf] = __builtin_amdgcn_mfma_f32_16x16x32_bf16(af[mf], bf[nf], acc[mf][nf], 0, 0, 0);
    }

    // epilogue: out [b,h,s,e] bf16
    #pragma unroll
    for (int mf = 0; mf < 4; ++mf)
        #pragma unroll
        for (int nf = 0; nf < 4; ++nf)
            #pragma unroll
            for (int r = 0; r < 4; ++r) {
                int m = m0 + wid * 64 + 16 * mf + (l >> 4) * 4 + r;
                int b = m >> 11, s = m & (S_ - 1);
                int e = 16 * nf + (l & 15);
                outw[((size_t)((b << 4) + h) * S_ + s) * E_ + e] = f2b(acc[mf][nf][r]);
            }
}

// ---------------- Flash attention (causal), bf16 MFMA ----------------
// grid (32 qt, 64 bh), 4 waves x 16 q-rows, KV tile 64.
__global__ __launch_bounds__(256) void flash(const ushort* __restrict__ qg,
                                             const ushort* __restrict__ kg,
                                             const ushort* __restrict__ vtg,
                                             ushort* __restrict__ attn) {
    const int qt = blockIdx.x;
    const int bh = blockIdx.y;
    const int b = bh >> 4, h = bh & 15;
    const ushort* qb = qg + (size_t)bh * (S_ * E_);
    const ushort* kb = kg + (size_t)bh * (S_ * E_);
    const ushort* vb = vtg + (size_t)bh * (E_ * S_);

    __shared__ __align__(16) ushort Qs[64 * 64];   // [q][e]   swizzled (8-chunk rows, c^(r&7))
    __shared__ __align__(16) ushort Ks[64 * 64];   // [t][e]   swizzled
    __shared__ __align__(16) ushort Vs[64 * 64];   // [e][j]   swizzled
    __shared__ __align__(16) ushort Ps[4][16 * 64];// per-wave [q16][j64] swizzled

    const int t = threadIdx.x, l = t & 63, wid = t >> 6;
    const float SC = 0.18033688f;                  // (1/sqrt(E)) * log2(e)

    #pragma unroll
    for (int it = 0; it < 2; ++it) {               // stage Q once
        int i = it * 256 + t;
        int r = i >> 3, cs = i & 7, c = cs ^ (r & 7);
        GLD16(qb + (size_t)(qt * 64 + r) * E_ + c * 8, &Qs[i * 8]);
    }

    short8 qf[2];
    floatx4 o[4] = {};
    float mr[4], lr[4];
    #pragma unroll
    for (int r = 0; r < 4; ++r) { mr[r] = -__builtin_inff(); lr[r] = 0.f; }
    const int ri_base = wid * 16 + ((l >> 4) << 2);

    for (int jt = 0; jt <= qt; ++jt) {
        __syncthreads();
        #pragma unroll
        for (int it = 0; it < 2; ++it) {           // stage K tile
            int i = it * 256 + t;
            int r = i >> 3, cs = i & 7, c = cs ^ (r & 7);
            GLD16(kb + (size_t)(jt * 64 + r) * E_ + c * 8, &Ks[i * 8]);
        }
        #pragma unroll
        for (int it = 0; it < 2; ++it) {           // stage V^T tile
            int i = it * 256 + t;
            int r = i >> 3, cs = i & 7, c = cs ^ (r & 7);
            GLD16(vb + (size_t)r * S_ + jt * 64 + c * 8, &Vs[i * 8]);
        }
        __syncthreads();

        if (jt == 0) {
            #pragma unroll
            for (int ks = 0; ks < 2; ++ks) {
                int row = wid * 16 + (l & 15);
                int c = ((l >> 4) + 4 * ks) ^ (row & 7);
                qf[ks] = *(const short8*)&Qs[row * 64 + c * 8];
            }
        }

        // S = Q K^T
        floatx4 s[4] = {};
        #pragma unroll
        for (int nf = 0; nf < 4; ++nf) {
            #pragma unroll
            for (int ks = 0; ks < 2; ++ks) {
                int row = 16 * nf + (l & 15);
                int c = ((l >> 4) + 4 * ks) ^ (row & 7);
                short8 kf = *(const short8*)&Ks[row * 64 + c * 8];
                s[nf] = __builtin_amdgcn_mfma_f32_16x16x32_bf16(qf[ks], kf, s[nf], 0, 0, 0);
            }
        }

        // scale (into log2 domain) + causal mask on diagonal tile
        const bool diag = (jt == qt);
        #pragma unroll
        for (int nf = 0; nf < 4; ++nf) {
            int cj = 16 * nf + (l & 15);
            #pragma unroll
            for (int r = 0; r < 4; ++r) {
                float v = s[nf][r] * SC;
                if (diag && cj > ri_base + r) v = -__builtin_inff();
                s[nf][r] = v;
            }
        }

        // online softmax (rows live across 16-lane groups)
        float al[4];
        #pragma unroll
        for (int r = 0; r < 4; ++r) {
            float mx = fmaxf(fmaxf(s[0][r], s[1][r]), fmaxf(s[2][r], s[3][r]));
            mx = fmaxf(mx, __shfl_xor(mx, 1));
            mx = fmaxf(mx, __shfl_xor(mx, 2));
            mx = fmaxf(mx, __shfl_xor(mx, 4));
            mx = fmaxf(mx, __shfl_xor(mx, 8));
            float mn = fmaxf(mr[r], mx);
            al[r] = fast_exp2(mr[r] - mn);
            mr[r] = mn;
            float rs = 0.f;
            #pragma unroll
            for (int nf = 0; nf < 4; ++nf) {
                float p = fast_exp2(s[nf][r] - mn);
                s[nf][r] = p;
                rs += p;
            }
            rs += __shfl_xor(rs, 1);
            rs += __shfl_xor(rs, 2);
            rs += __shfl_xor(rs, 4);
            rs += __shfl_xor(rs, 8);
            lr[r] = lr[r] * al[r] + rs;
            #pragma unroll
            for (int nf = 0; nf < 4; ++nf) o[nf][r] *= al[r];
        }

        // P -> wave-private LDS (bf16, swizzled)
        #pragma unroll
        for (int nf = 0; nf < 4; ++nf)
            #pragma unroll
            for (int r = 0; r < 4; ++r) {
                int row = (l >> 4) * 4 + r;
                int col = 16 * nf + (l & 15);
                int sw = (col >> 3) ^ (row & 7);
                Ps[wid][row * 64 + sw * 8 + (col & 7)] = f2b(s[nf][r]);
            }

        // O += P V
        short8 pf[2];
        #pragma unroll
        for (int ks = 0; ks < 2; ++ks) {
            int row = l & 15;
            int c = ((l >> 4) + 4 * ks) ^ (row & 7);
            pf[ks] = *(const short8*)&Ps[wid][row * 64 + c * 8];
        }
        #pragma unroll
        for (int nf = 0; nf < 4; ++nf) {
            #pragma unroll
            for (int ks = 0; ks < 2; ++ks) {
                int row = 16 * nf + (l & 15);
                int c = ((l >> 4) + 4 * ks) ^ (row & 7);
                short8 vf = *(const short8*)&Vs[row * 64 + c * 8];
                o[nf] = __builtin_amdgcn_mfma_f32_16x16x32_bf16(pf[ks], vf, o[nf], 0, 0, 0);
            }
        }
    }

    // epilogue: normalize, bounce via Ps for coalesced bf16 writes
    #pragma unroll
    for (int r = 0; r < 4; ++r) {
        float inv = 1.0f / lr[r];
        #pragma unroll
        for (int nf = 0; nf < 4; ++nf) {
            int row = (l >> 4) * 4 + r;
            int col = 16 * nf + (l & 15);
            int sw = (col >> 3) ^ (row & 7);
            Ps[wid][row * 64 + sw * 8 + (col & 7)] = f2b(o[nf][r] * inv);
        }
    }
    #pragma unroll
    for (int it = 0; it < 2; ++it) {               // 16 rows x 8 chunks per wave
        int i = it * 64 + l;
        int row = i >> 3, cc = i & 7;
        int c = cc ^ (row & 7);
        short8 vv = *(const short8*)&Ps[wid][row * 64 + c * 8];
        int s_abs = qt * 64 + wid * 16 + row;
        *(short8*)&attn[((size_t)(b * S_ + s_abs)) * D_ + h * E_ + cc * 8] = vv;
    }
}

// ---------------- output projection: [8192x1024] x Wp^T + bp, bf16 MFMA, fp32 out ----------------
// tile 128x128, BK=32, waves 2x2 (64x64 each), 16 mfma / wave / K-step.
__global__ __launch_bounds__(256) void out_proj(const ushort* __restrict__ a,
                                                const ushort* __restrict__ wpb,
                                                const float* __restrict__ bp,
                                                float* __restrict__ out) {
    const int m0 = blockIdx.x * 128;
    const int n0 = blockIdx.y * 128;

    __shared__ __align__(16) ushort As[128 * 32];
    __shared__ __align__(16) ushort Bs[128 * 32];

    const int t = threadIdx.x, l = t & 63, wid = t >> 6;
    const int wm = (wid & 1) * 64, wn = (wid >> 1) * 64;
    floatx4 acc[4][4] = {};

    for (int k0 = 0; k0 < D_; k0 += 32) {
        __syncthreads();
        #pragma unroll
        for (int it = 0; it < 2; ++it) {
            int i = it * 256 + t;
            int r = i >> 2, cs = i & 3;
            int c = cs ^ ((r >> 1) & 3);
            GLD16(a + (size_t)(m0 + r) * D_ + k0 + c * 8, &As[i * 8]);
            GLD16(wpb + (size_t)(n0 + r) * D_ + k0 + c * 8, &Bs[i * 8]);
        }
        __syncthreads();

        short8 af[4], bf[4];
        #pragma unroll
        for (int mf = 0; mf < 4; ++mf) {
            int row = wm + 16 * mf + (l & 15);
            int c = (l >> 4) ^ ((row >> 1) & 3);
            af[mf] = *(const short8*)&As[row * 32 + c * 8];
        }
        #pragma unroll
        for (int nf = 0; nf < 4; ++nf) {
            int row = wn + 16 * nf + (l & 15);
            int c = (l >> 4) ^ ((row >> 1) & 3);
            bf[nf] = *(const short8*)&Bs[row * 32 + c * 8];
        }
        #pragma unroll
        for (int mf = 0; mf < 4; ++mf)
            #pragma unroll
            for (int nf = 0; nf < 4; ++nf)
                acc[mf][nf] = __builtin_amdgcn_mfma_f32_16x16x32_bf16(af[mf], bf[nf], acc[mf][nf], 0, 0, 0);
    }

    #pragma unroll
    for (int nf = 0; nf < 4; ++nf) {
        int col = n0 + wn + 16 * nf + (l & 15);
        float bias = bp[col];
        #pragma unroll
        for (int mf = 0; mf < 4; ++mf)
            #pragma unroll
            for (int r = 0; r < 4; ++r) {
                int m = m0 + wm + 16 * mf + (l >> 4) * 4 + r;
                out[(size_t)m * D_ + col] = acc[mf][nf][r] + bias;
            }
    }
}

extern "C" void kernel_launch(void* const* d_in, const int* in_sizes, int n_in,
                              void* d_out, int out_size, void* d_ws, size_t ws_size,
                              hipStream_t stream) {
    const float* x  = (const float*)d_in[0];
    const float* Wq = (const float*)d_in[1];
    const float* Wk = (const float*)d_in[2];
    const float* Wv = (const float*)d_in[3];
    const float* Wp = (const float*)d_in[4];
    const float* bp = (const float*)d_in[5];

    ushort* ws = (ushort*)d_ws;
    const size_t NX  = (size_t)M_ * D_;          // 8M
    const size_t NW  = (size_t)48 * E_ * D_;     // 3.15M
    const size_t NP  = (size_t)D_ * D_;          // 1M
    const size_t QSZ = (size_t)B_ * H_ * S_ * E_;// 8M
    ushort* xb    = ws;
    ushort* wt    = xb + NX;
    ushort* wpb   = wt + NW;
    ushort* qkvb  = wpb + NP;        // q | k | v
    ushort* vt    = qkvb + 3 * QSZ;
    ushort* attnb = vt + QSZ;        // total ~104 MB

    cast_bf16  <<<2048, 256, 0, stream>>>(x, xb, (int)(NX / 8));
    cast_bf16  <<<512, 256, 0, stream>>>(Wp, wpb, (int)(NP / 8));
    transpose_w<<<dim3(16, 48), 256, 0, stream>>>(Wq, Wk, Wv, wt);
    gemm_qkv   <<<dim3(M_ / 256, 48), 256, 0, stream>>>(xb, wt, qkvb);
    transpose_v<<<dim3(S_ / 64, B_ * H_), 256, 0, stream>>>(qkvb + 2 * QSZ, vt);
    flash      <<<dim3(S_ / 64, B_ * H_), 256, 0, stream>>>(qkvb, qkvb + QSZ, vt, attnb);
    out_proj   <<<dim3(M_ / 128, D_ / 128), 256, 0, stream>>>(attnb, wpb, bp, (float*)d_out);
}

// Round 5
// 250.293 us; speedup vs baseline: 7.5072x; 1.3712x over previous
//
#include <hip/hip_runtime.h>

#define B_ 4
#define S_ 2048
#define D_ 1024
#define H_ 16
#define E_ 64
#define M_ (B_*S_)   // 8192

typedef __attribute__((ext_vector_type(8))) short short8;   // 8 bf16 = 4 VGPRs (MFMA A/B frag)
typedef __attribute__((ext_vector_type(4))) float floatx4;  // MFMA C/D frag

// async global->LDS, 16B per lane; dest must be linear (wave base + lane*16)
#define GLD16(g, l) __builtin_amdgcn_global_load_lds( \
    (const __attribute__((address_space(1))) unsigned*)(g), \
    (__attribute__((address_space(3))) unsigned*)(l), 16, 0, 0)

__device__ __forceinline__ ushort f2b(float f) {   // fp32 -> bf16 RNE
    union { float f; unsigned u; } v; v.f = f;
    unsigned r = v.u + 0x7fffu + ((v.u >> 16) & 1u);
    return (ushort)(r >> 16);
}
__device__ __forceinline__ float fast_exp2(float x) {
#if __has_builtin(__builtin_amdgcn_exp2f)
    return __builtin_amdgcn_exp2f(x);
#else
    float r; asm("v_exp_f32 %0, %1" : "=v"(r) : "v"(x)); return r;
#endif
}

// ---------------- plain cast fp32 -> bf16 (vector8) ----------------
__global__ __launch_bounds__(256) void cast_bf16(const float* __restrict__ in,
                                                 ushort* __restrict__ out, int n8) {
    int i = blockIdx.x * 256 + threadIdx.x;
    int stride = gridDim.x * 256;
    for (; i < n8; i += stride) {
        float4 a = ((const float4*)in)[2 * i];
        float4 b = ((const float4*)in)[2 * i + 1];
        short8 o;
        o[0] = (short)f2b(a.x); o[1] = (short)f2b(a.y);
        o[2] = (short)f2b(a.z); o[3] = (short)f2b(a.w);
        o[4] = (short)f2b(b.x); o[5] = (short)f2b(b.y);
        o[6] = (short)f2b(b.z); o[7] = (short)f2b(b.w);
        ((short8*)out)[i] = o;
    }
}

// ---------------- W cast+transpose: [48][D][E] fp32 -> [48][E][D] bf16 ----------------
__global__ __launch_bounds__(256) void transpose_w(const float* __restrict__ Wq,
                                                   const float* __restrict__ Wk,
                                                   const float* __restrict__ Wv,
                                                   ushort* __restrict__ wt) {
    int g = blockIdx.y;                 // 0..47 (w*16+h)
    int d0 = blockIdx.x * 64;
    const float* W = (g < 16 ? Wq : (g < 32 ? Wk : Wv)) + (size_t)(g & 15) * (D_ * E_);
    __shared__ __align__(16) ushort T[64 * 80];   // T[e][d-col], pitch 80
    int t = threadIdx.x;
    #pragma unroll
    for (int it = 0; it < 4; ++it) {               // 64 d-rows x 16 float4 cols
        int i = it * 256 + t;
        int r = i >> 4, c = i & 15;
        float4 x = *(const float4*)(W + (size_t)(d0 + r) * E_ + c * 4);
        T[(c * 4 + 0) * 80 + r] = f2b(x.x);
        T[(c * 4 + 1) * 80 + r] = f2b(x.y);
        T[(c * 4 + 2) * 80 + r] = f2b(x.z);
        T[(c * 4 + 3) * 80 + r] = f2b(x.w);
    }
    __syncthreads();
    #pragma unroll
    for (int it = 0; it < 2; ++it) {               // 64 e-rows x 8 chunks of 8
        int i = it * 256 + t;
        int e = i >> 3, c = i & 7;
        short8 x = *(const short8*)&T[e * 80 + c * 8];
        *(short8*)&wt[((size_t)g * E_ + e) * D_ + d0 + c * 8] = x;
    }
}

// ---------------- V transpose: [bh][S][E] -> [bh][E][S] (bf16) ----------------
__global__ __launch_bounds__(256) void transpose_v(const ushort* __restrict__ v,
                                                   ushort* __restrict__ vt) {
    int s0 = blockIdx.x * 64;
    int bh = blockIdx.y;
    __shared__ __align__(16) ushort T[64 * 80];   // T[e][s-col]
    int t = threadIdx.x;
    #pragma unroll
    for (int it = 0; it < 2; ++it) {
        int i = it * 256 + t;
        int r = i >> 3, c = i & 7;                 // s-row r, e-chunk c
        short8 x = *(const short8*)&v[((size_t)bh * S_ + s0 + r) * E_ + c * 8];
        #pragma unroll
        for (int j = 0; j < 8; ++j) T[(c * 8 + j) * 80 + r] = (ushort)x[j];
    }
    __syncthreads();
    #pragma unroll
    for (int it = 0; it < 2; ++it) {
        int i = it * 256 + t;
        int e = i >> 3, c = i & 7;
        short8 x = *(const short8*)&T[e * 80 + c * 8];
        *(short8*)&vt[((size_t)bh * E_ + e) * S_ + s0 + c * 8] = x;
    }
}

// ---------------- QKV GEMM: [8192 x 1024] x [1024 x 64] per (w,h), bf16 MFMA ----------------
__global__ __launch_bounds__(256) void gemm_qkv(const ushort* __restrict__ xb,
                                                const ushort* __restrict__ wt,
                                                ushort* __restrict__ qkv) {
    const int m0 = blockIdx.x * 256;
    const int wh = blockIdx.y;           // 0..47
    const ushort* Wg = wt + (size_t)wh * (E_ * D_);
    ushort* outw = qkv + (size_t)(wh >> 4) * ((size_t)B_ * H_ * S_ * E_);
    const int h = wh & 15;

    __shared__ __align__(16) ushort As[256 * 32];   // [256][32] swizzled
    __shared__ __align__(16) ushort Bs[64 * 32];    // [64][32]  swizzled

    const int t = threadIdx.x, l = t & 63, wid = t >> 6;
    floatx4 acc[4][4] = {};

    for (int k0 = 0; k0 < D_; k0 += 32) {
        __syncthreads();
        #pragma unroll
        for (int it = 0; it < 4; ++it) {            // A: 1024 chunks
            int i = it * 256 + t;
            int r = i >> 2, cs = i & 3;
            int c = cs ^ ((r >> 1) & 3);
            GLD16(xb + (size_t)(m0 + r) * D_ + k0 + c * 8, &As[i * 8]);
        }
        {                                            // B: 256 chunks
            int r = t >> 2, cs = t & 3;
            int c = cs ^ ((r >> 1) & 3);
            GLD16(Wg + (size_t)r * D_ + k0 + c * 8, &Bs[t * 8]);
        }
        __syncthreads();

        short8 af[4], bf[4];
        #pragma unroll
        for (int mf = 0; mf < 4; ++mf) {
            int row = wid * 64 + 16 * mf + (l & 15);
            int c = (l >> 4) ^ ((row >> 1) & 3);
            af[mf] = *(const short8*)&As[row * 32 + c * 8];
        }
        #pragma unroll
        for (int nf = 0; nf < 4; ++nf) {
            int row = 16 * nf + (l & 15);
            int c = (l >> 4) ^ ((row >> 1) & 3);
            bf[nf] = *(const short8*)&Bs[row * 32 + c * 8];
        }
        #pragma unroll
        for (int mf = 0; mf < 4; ++mf)
            #pragma unroll
            for (int nf = 0; nf < 4; ++nf)
                acc[mf][nf] = __builtin_amdgcn_mfma_f32_16x16x32_bf16(af[mf], bf[nf], acc[mf][nf], 0, 0, 0);
    }

    #pragma unroll
    for (int mf = 0; mf < 4; ++mf)
        #pragma unroll
        for (int nf = 0; nf < 4; ++nf)
            #pragma unroll
            for (int r = 0; r < 4; ++r) {
                int m = m0 + wid * 64 + 16 * mf + (l >> 4) * 4 + r;
                int b = m >> 11, s = m & (S_ - 1);
                int e = 16 * nf + (l & 15);
                outw[((size_t)((b << 4) + h) * S_ + s) * E_ + e] = f2b(acc[mf][nf][r]);
            }
}

// ---------------- Flash attention (causal), bf16 MFMA, 2-phase pipelined ----------------
// grid: 512 1-D blocks. Block n: xq = n>>6 (0..7), bh = n&63 (XCD = bh%8 -> per-XCD L2-resident K/V).
// Each block does 4 balanced q-tiles {xq, 15-xq, 16+xq, 31-xq} = 66 KV-tiles exactly.
// K/V double-buffered in LDS; next tile's global_load_lds issued BEFORE current tile's compute.
__global__ __launch_bounds__(256) void flash(const ushort* __restrict__ qg,
                                             const ushort* __restrict__ kg,
                                             const ushort* __restrict__ vtg,
                                             ushort* __restrict__ attn) {
    const int n = blockIdx.x;
    const int xq = n >> 6;
    const int bh = n & 63;
    const int b = bh >> 4, h = bh & 15;
    const ushort* qb = qg + (size_t)bh * (S_ * E_);
    const ushort* kb = kg + (size_t)bh * (S_ * E_);
    const ushort* vb = vtg + (size_t)bh * (E_ * S_);

    __shared__ __align__(16) ushort Qs[64 * 64];      // [q][e]   swizzled
    __shared__ __align__(16) ushort Ks[2][64 * 64];   // [t][e]   swizzled, double-buffered
    __shared__ __align__(16) ushort Vs[2][64 * 64];   // [e][j]   swizzled, double-buffered
    __shared__ __align__(16) ushort Ps[4][16 * 64];   // per-wave [q16][j64] swizzled

    const int t = threadIdx.x, l = t & 63, wid = t >> 6;
    const float SC = 0.18033688f;                  // (1/sqrt(E)) * log2(e)
    const int ri_base = wid * 16 + ((l >> 4) << 2);
    const int qts[4] = {xq, 15 - xq, 16 + xq, 31 - xq};

    #pragma unroll 1
    for (int qi = 0; qi < 4; ++qi) {
        const int qt = qts[qi];

        // prologue: stage Q + first K/V tile
        #pragma unroll
        for (int it = 0; it < 2; ++it) {
            int i = it * 256 + t;
            int r = i >> 3, cs = i & 7, c = cs ^ (r & 7);
            GLD16(qb + (size_t)(qt * 64 + r) * E_ + c * 8, &Qs[i * 8]);
            GLD16(kb + (size_t)r * E_ + c * 8, &Ks[0][i * 8]);
            GLD16(vb + (size_t)r * S_ + c * 8, &Vs[0][i * 8]);
        }
        __syncthreads();

        short8 qf[2];
        #pragma unroll
        for (int ks = 0; ks < 2; ++ks) {
            int row = wid * 16 + (l & 15);
            int c = ((l >> 4) + 4 * ks) ^ (row & 7);
            qf[ks] = *(const short8*)&Qs[row * 64 + c * 8];
        }

        floatx4 o[4] = {};
        float mr[4], lr[4];
        #pragma unroll
        for (int r = 0; r < 4; ++r) { mr[r] = -__builtin_inff(); lr[r] = 0.f; }

        int buf = 0;
        for (int jt = 0; jt <= qt; ++jt) {
            // issue next tile's staging BEFORE compute (latency hides under compute)
            if (jt < qt) {
                #pragma unroll
                for (int it = 0; it < 2; ++it) {
                    int i = it * 256 + t;
                    int r = i >> 3, cs = i & 7, c = cs ^ (r & 7);
                    GLD16(kb + (size_t)((jt + 1) * 64 + r) * E_ + c * 8, &Ks[buf ^ 1][i * 8]);
                    GLD16(vb + (size_t)r * S_ + (jt + 1) * 64 + c * 8, &Vs[buf ^ 1][i * 8]);
                }
            }

            // S = Q K^T on current buffer
            floatx4 s[4] = {};
            #pragma unroll
            for (int nf = 0; nf < 4; ++nf) {
                #pragma unroll
                for (int ks = 0; ks < 2; ++ks) {
                    int row = 16 * nf + (l & 15);
                    int c = ((l >> 4) + 4 * ks) ^ (row & 7);
                    short8 kf = *(const short8*)&Ks[buf][row * 64 + c * 8];
                    s[nf] = __builtin_amdgcn_mfma_f32_16x16x32_bf16(qf[ks], kf, s[nf], 0, 0, 0);
                }
            }

            // scale (log2 domain) + causal mask on diagonal tile
            const bool diag = (jt == qt);
            #pragma unroll
            for (int nf = 0; nf < 4; ++nf) {
                int cj = 16 * nf + (l & 15);
                #pragma unroll
                for (int r = 0; r < 4; ++r) {
                    float v = s[nf][r] * SC;
                    if (diag && cj > ri_base + r) v = -__builtin_inff();
                    s[nf][r] = v;
                }
            }

            // online softmax (rows live across 16-lane groups)
            float al[4];
            #pragma unroll
            for (int r = 0; r < 4; ++r) {
                float mx = fmaxf(fmaxf(s[0][r], s[1][r]), fmaxf(s[2][r], s[3][r]));
                mx = fmaxf(mx, __shfl_xor(mx, 1));
                mx = fmaxf(mx, __shfl_xor(mx, 2));
                mx = fmaxf(mx, __shfl_xor(mx, 4));
                mx = fmaxf(mx, __shfl_xor(mx, 8));
                float mn = fmaxf(mr[r], mx);
                al[r] = fast_exp2(mr[r] - mn);
                mr[r] = mn;
                float rs = 0.f;
                #pragma unroll
                for (int nf = 0; nf < 4; ++nf) {
                    float p = fast_exp2(s[nf][r] - mn);
                    s[nf][r] = p;
                    rs += p;
                }
                rs += __shfl_xor(rs, 1);
                rs += __shfl_xor(rs, 2);
                rs += __shfl_xor(rs, 4);
                rs += __shfl_xor(rs, 8);
                lr[r] = lr[r] * al[r] + rs;
                #pragma unroll
                for (int nf = 0; nf < 4; ++nf) o[nf][r] *= al[r];
            }

            // P -> wave-private LDS (bf16, swizzled)
            #pragma unroll
            for (int nf = 0; nf < 4; ++nf)
                #pragma unroll
                for (int r = 0; r < 4; ++r) {
                    int row = (l >> 4) * 4 + r;
                    int col = 16 * nf + (l & 15);
                    int sw = (col >> 3) ^ (row & 7);
                    Ps[wid][row * 64 + sw * 8 + (col & 7)] = f2b(s[nf][r]);
                }

            // O += P V
            short8 pf[2];
            #pragma unroll
            for (int ks = 0; ks < 2; ++ks) {
                int row = l & 15;
                int c = ((l >> 4) + 4 * ks) ^ (row & 7);
                pf[ks] = *(const short8*)&Ps[wid][row * 64 + c * 8];
            }
            #pragma unroll
            for (int nf = 0; nf < 4; ++nf) {
                #pragma unroll
                for (int ks = 0; ks < 2; ++ks) {
                    int row = 16 * nf + (l & 15);
                    int c = ((l >> 4) + 4 * ks) ^ (row & 7);
                    short8 vf = *(const short8*)&Vs[buf][row * 64 + c * 8];
                    o[nf] = __builtin_amdgcn_mfma_f32_16x16x32_bf16(pf[ks], vf, o[nf], 0, 0, 0);
                }
            }

            __syncthreads();   // drains this iteration's prefetch (vmcnt) + protects buf^1
            buf ^= 1;
        }

        // epilogue: normalize, bounce via Ps for coalesced bf16 writes
        #pragma unroll
        for (int r = 0; r < 4; ++r) {
            float inv = 1.0f / lr[r];
            #pragma unroll
            for (int nf = 0; nf < 4; ++nf) {
                int row = (l >> 4) * 4 + r;
                int col = 16 * nf + (l & 15);
                int sw = (col >> 3) ^ (row & 7);
                Ps[wid][row * 64 + sw * 8 + (col & 7)] = f2b(o[nf][r] * inv);
            }
        }
        #pragma unroll
        for (int it = 0; it < 2; ++it) {
            int i = it * 64 + l;
            int row = i >> 3, cc = i & 7;
            int c = cc ^ (row & 7);
            short8 vv = *(const short8*)&Ps[wid][row * 64 + c * 8];
            int s_abs = qt * 64 + wid * 16 + row;
            *(short8*)&attn[((size_t)(b * S_ + s_abs)) * D_ + h * E_ + cc * 8] = vv;
        }
    }
}

// ---------------- output projection: [8192x1024] x Wp^T + bp, bf16 MFMA, fp32 out ----------------
__global__ __launch_bounds__(256) void out_proj(const ushort* __restrict__ a,
                                                const ushort* __restrict__ wpb,
                                                const float* __restrict__ bp,
                                                float* __restrict__ out) {
    const int m0 = blockIdx.x * 128;
    const int n0 = blockIdx.y * 128;

    __shared__ __align__(16) ushort As[128 * 32];
    __shared__ __align__(16) ushort Bs[128 * 32];

    const int t = threadIdx.x, l = t & 63, wid = t >> 6;
    const int wm = (wid & 1) * 64, wn = (wid >> 1) * 64;
    floatx4 acc[4][4] = {};

    for (int k0 = 0; k0 < D_; k0 += 32) {
        __syncthreads();
        #pragma unroll
        for (int it = 0; it < 2; ++it) {
            int i = it * 256 + t;
            int r = i >> 2, cs = i & 3;
            int c = cs ^ ((r >> 1) & 3);
            GLD16(a + (size_t)(m0 + r) * D_ + k0 + c * 8, &As[i * 8]);
            GLD16(wpb + (size_t)(n0 + r) * D_ + k0 + c * 8, &Bs[i * 8]);
        }
        __syncthreads();

        short8 af[4], bf[4];
        #pragma unroll
        for (int mf = 0; mf < 4; ++mf) {
            int row = wm + 16 * mf + (l & 15);
            int c = (l >> 4) ^ ((row >> 1) & 3);
            af[mf] = *(const short8*)&As[row * 32 + c * 8];
        }
        #pragma unroll
        for (int nf = 0; nf < 4; ++nf) {
            int row = wn + 16 * nf + (l & 15);
            int c = (l >> 4) ^ ((row >> 1) & 3);
            bf[nf] = *(const short8*)&Bs[row * 32 + c * 8];
        }
        #pragma unroll
        for (int mf = 0; mf < 4; ++mf)
            #pragma unroll
            for (int nf = 0; nf < 4; ++nf)
                acc[mf][nf] = __builtin_amdgcn_mfma_f32_16x16x32_bf16(af[mf], bf[nf], acc[mf][nf], 0, 0, 0);
    }

    #pragma unroll
    for (int nf = 0; nf < 4; ++nf) {
        int col = n0 + wn + 16 * nf + (l & 15);
        float bias = bp[col];
        #pragma unroll
        for (int mf = 0; mf < 4; ++mf)
            #pragma unroll
            for (int r = 0; r < 4; ++r) {
                int m = m0 + wm + 16 * mf + (l >> 4) * 4 + r;
                out[(size_t)m * D_ + col] = acc[mf][nf][r] + bias;
            }
    }
}

extern "C" void kernel_launch(void* const* d_in, const int* in_sizes, int n_in,
                              void* d_out, int out_size, void* d_ws, size_t ws_size,
                              hipStream_t stream) {
    const float* x  = (const float*)d_in[0];
    const float* Wq = (const float*)d_in[1];
    const float* Wk = (const float*)d_in[2];
    const float* Wv = (const float*)d_in[3];
    const float* Wp = (const float*)d_in[4];
    const float* bp = (const float*)d_in[5];

    ushort* ws = (ushort*)d_ws;
    const size_t NX  = (size_t)M_ * D_;          // 8M
    const size_t NW  = (size_t)48 * E_ * D_;     // 3.15M
    const size_t NP  = (size_t)D_ * D_;          // 1M
    const size_t QSZ = (size_t)B_ * H_ * S_ * E_;// 8M
    ushort* xb    = ws;
    ushort* wt    = xb + NX;
    ushort* wpb   = wt + NW;
    ushort* qkvb  = wpb + NP;        // q | k | v
    ushort* vt    = qkvb + 3 * QSZ;
    ushort* attnb = vt + QSZ;        // total ~104 MB

    cast_bf16  <<<2048, 256, 0, stream>>>(x, xb, (int)(NX / 8));
    cast_bf16  <<<512, 256, 0, stream>>>(Wp, wpb, (int)(NP / 8));
    transpose_w<<<dim3(16, 48), 256, 0, stream>>>(Wq, Wk, Wv, wt);
    gemm_qkv   <<<dim3(M_ / 256, 48), 256, 0, stream>>>(xb, wt, qkvb);
    transpose_v<<<dim3(S_ / 64, B_ * H_), 256, 0, stream>>>(qkvb + 2 * QSZ, vt);
    flash      <<<512, 256, 0, stream>>>(qkvb, qkvb + QSZ, vt, attnb);
    out_proj   <<<dim3(M_ / 128, D_ / 128), 256, 0, stream>>>(attnb, wpb, bp, (float*)d_out);
}